// Round 3
// baseline (2013.183 us; speedup 1.0000x reference)
//
#include <hip/hip_runtime.h>
#include <hip/hip_bf16.h>

// GPT forward: L=4, B=2, S=1024, D=768, H=12, DK=64, DI=3072, V=512
// R3: pre-converted bf16 transposed weights + fused QKV + m97-style GEMM
//     (global_load_lds width-16, BK=64, 128/64 x 128 tiles).

#define TKN    2048
#define DMODEL 768
#define SEQ    1024
#define NH     12
#define DHEAD  64
#define DFF    3072
#define NL     4
#define NVOCAB 512
#define NQKV   2304   // 3*DMODEL

typedef unsigned short u16;
typedef __attribute__((ext_vector_type(4))) float f32x4;
typedef __attribute__((ext_vector_type(8))) short short8;
typedef __attribute__((ext_vector_type(4))) unsigned short us4;
typedef __attribute__((ext_vector_type(4))) unsigned int u32x4;

__device__ __forceinline__ u16 f2bf(float f) {
  unsigned u = __builtin_bit_cast(unsigned, f);
  u += 0x7fffu + ((u >> 16) & 1u);   // RNE
  return (u16)(u >> 16);
}

__device__ __forceinline__ short8 mk8(us4 lo, us4 hi) {
  short8 r;
  r[0] = (short)lo[0]; r[1] = (short)lo[1]; r[2] = (short)lo[2]; r[3] = (short)lo[3];
  r[4] = (short)hi[0]; r[5] = (short)hi[1]; r[6] = (short)hi[2]; r[7] = (short)hi[3];
  return r;
}

// async global->LDS, 16B per lane; lds dest = wave-uniform base + lane*16
__device__ __forceinline__ void gload16(const u16* g, u16* l) {
  __builtin_amdgcn_global_load_lds(
      (const __attribute__((address_space(1))) unsigned int*)g,
      (__attribute__((address_space(3))) unsigned int*)l, 16, 0, 0);
}

// ---------------- embedding ----------------
__global__ __launch_bounds__(256) void k_embed(const int* __restrict__ x,
                                               const float* __restrict__ emb,
                                               const float* __restrict__ pos,
                                               float* __restrict__ h) {
  int t = blockIdx.x;
  int s = t & (SEQ - 1);
  int id = x[t];
  int d = threadIdx.x;
#pragma unroll
  for (int j = 0; j < 3; ++j, d += 256)
    h[t * DMODEL + d] = emb[id * DMODEL + d] + pos[s * DMODEL + d];
}

// ---------------- layernorm (f32 in -> bf16 out) ----------------
__global__ __launch_bounds__(256) void k_ln(const float* __restrict__ h,
                                            const float* __restrict__ gam,
                                            const float* __restrict__ bet,
                                            u16* __restrict__ out) {
  __shared__ float sbuf[8];
  int row = blockIdx.x, tid = threadIdx.x;
  const float* hr = h + (size_t)row * DMODEL;
  float x0 = hr[tid], x1 = hr[tid + 256], x2 = hr[tid + 512];
  float s = x0 + x1 + x2;
#pragma unroll
  for (int off = 32; off > 0; off >>= 1) s += __shfl_down(s, off);
  if ((tid & 63) == 0) sbuf[tid >> 6] = s;
  __syncthreads();
  float mu = (sbuf[0] + sbuf[1] + sbuf[2] + sbuf[3]) * (1.0f / DMODEL);
  float d0 = x0 - mu, d1 = x1 - mu, d2 = x2 - mu;
  float v = d0 * d0 + d1 * d1 + d2 * d2;
#pragma unroll
  for (int off = 32; off > 0; off >>= 1) v += __shfl_down(v, off);
  if ((tid & 63) == 0) sbuf[4 + (tid >> 6)] = v;
  __syncthreads();
  float var = (sbuf[4] + sbuf[5] + sbuf[6] + sbuf[7]) * (1.0f / DMODEL);
  float rstd = rsqrtf(var + 1e-5f);
  size_t o = (size_t)row * DMODEL;
  out[o + tid]       = f2bf(d0 * rstd * gam[tid]       + bet[tid]);
  out[o + tid + 256] = f2bf(d1 * rstd * gam[tid + 256] + bet[tid + 256]);
  out[o + tid + 512] = f2bf(d2 * rstd * gam[tid + 512] + bet[tid + 512]);
}

// ---------------- weight convert+transpose: dst[n][k] = bf16(src[k][n]) ----------------
__global__ __launch_bounds__(256) void k_cvtT(const float* __restrict__ src,
                                              u16* __restrict__ dst,
                                              int K, int N) {
  __shared__ u16 tl[64][72];
  int k0 = blockIdx.x * 64, n0 = blockIdx.y * 64;
  int t = threadIdx.x;
  int kr = t >> 2, nj = (t & 3) << 4;
  const float* sp = src + (size_t)(k0 + kr) * N + n0 + nj;
  float4 a0 = ((const float4*)sp)[0];
  float4 a1 = ((const float4*)sp)[1];
  float4 a2 = ((const float4*)sp)[2];
  float4 a3 = ((const float4*)sp)[3];
  u16* tr = &tl[kr][nj];
  tr[0]=f2bf(a0.x); tr[1]=f2bf(a0.y); tr[2]=f2bf(a0.z); tr[3]=f2bf(a0.w);
  tr[4]=f2bf(a1.x); tr[5]=f2bf(a1.y); tr[6]=f2bf(a1.z); tr[7]=f2bf(a1.w);
  tr[8]=f2bf(a2.x); tr[9]=f2bf(a2.y); tr[10]=f2bf(a2.z); tr[11]=f2bf(a2.w);
  tr[12]=f2bf(a3.x); tr[13]=f2bf(a3.y); tr[14]=f2bf(a3.z); tr[15]=f2bf(a3.w);
  __syncthreads();
  int nr = t >> 2, kj = (t & 3) << 4;
  us4 o[4];
#pragma unroll
  for (int c = 0; c < 4; ++c)
#pragma unroll
    for (int i = 0; i < 4; ++i) o[c][i] = tl[kj + c * 4 + i][nr];
  u16* dp = dst + (size_t)(n0 + nr) * K + k0 + kj;
  ((us4*)dp)[0] = o[0]; ((us4*)dp)[1] = o[1];
  ((us4*)dp)[2] = o[2]; ((us4*)dp)[3] = o[3];
}

// fused QKV weight convert: dst[2304][768], rows 0-767=wq^T, 768-1535=wk^T, 1536-2303=wv^T
__global__ __launch_bounds__(256) void k_cvtQKV(const float* __restrict__ wq,
                                                const float* __restrict__ wk,
                                                const float* __restrict__ wv,
                                                u16* __restrict__ dst) {
  __shared__ u16 tl[64][72];
  int k0 = blockIdx.x * 64, gn0 = blockIdx.y * 64;
  int sel = gn0 / DMODEL;
  int n0 = gn0 - sel * DMODEL;
  const float* src = sel == 0 ? wq : sel == 1 ? wk : wv;
  int t = threadIdx.x;
  int kr = t >> 2, nj = (t & 3) << 4;
  const float* sp = src + (size_t)(k0 + kr) * DMODEL + n0 + nj;
  float4 a0 = ((const float4*)sp)[0];
  float4 a1 = ((const float4*)sp)[1];
  float4 a2 = ((const float4*)sp)[2];
  float4 a3 = ((const float4*)sp)[3];
  u16* tr = &tl[kr][nj];
  tr[0]=f2bf(a0.x); tr[1]=f2bf(a0.y); tr[2]=f2bf(a0.z); tr[3]=f2bf(a0.w);
  tr[4]=f2bf(a1.x); tr[5]=f2bf(a1.y); tr[6]=f2bf(a1.z); tr[7]=f2bf(a1.w);
  tr[8]=f2bf(a2.x); tr[9]=f2bf(a2.y); tr[10]=f2bf(a2.z); tr[11]=f2bf(a2.w);
  tr[12]=f2bf(a3.x); tr[13]=f2bf(a3.y); tr[14]=f2bf(a3.z); tr[15]=f2bf(a3.w);
  __syncthreads();
  int nr = t >> 2, kj = (t & 3) << 4;
  us4 o[4];
#pragma unroll
  for (int c = 0; c < 4; ++c)
#pragma unroll
    for (int i = 0; i < 4; ++i) o[c][i] = tl[kj + c * 4 + i][nr];
  u16* dp = dst + (size_t)(gn0 + nr) * DMODEL + k0 + kj;
  ((us4*)dp)[0] = o[0]; ((us4*)dp)[1] = o[1];
  ((us4*)dp)[2] = o[2]; ((us4*)dp)[3] = o[3];
}

// pack fused QKV bias for all layers: dst[l*2304 + j]
__global__ __launch_bounds__(256) void k_packb(const float* __restrict__ bq,
                                               const float* __restrict__ bk,
                                               const float* __restrict__ bv,
                                               float* __restrict__ dst) {
  int i = blockIdx.x * 256 + threadIdx.x;
  if (i < NL * NQKV) {
    int l = i / NQKV, j = i - l * NQKV;
    float v = j < DMODEL ? bq[l * DMODEL + j]
            : j < 2 * DMODEL ? bk[l * DMODEL + j - DMODEL]
            : bv[l * DMODEL + j - 2 * DMODEL];
    dst[i] = v;
  }
}

// ---------------- GEMM: C[M,N] = A[M,K](bf16) * BT[N,K](bf16) ----------------
// EP 0: out bf16 = acc + bias (stride N)   EP 1: out f32 += acc + bias
// EP 2: out bf16 = gelu(acc + bias)        EP 3: out f32 = acc
// BMv x 128 tile, BK=64, 4 waves, wave quadrant (BMv/2) x 64.
template <int EP, int BMv>
__global__ __launch_bounds__(256) void k_mm(const u16* __restrict__ A,
                                            const u16* __restrict__ BT,
                                            const float* __restrict__ bias,
                                            void* __restrict__ outp,
                                            int N, int K) {
  constexpr int MI = BMv / 32;          // frag rows per wave, also A stage issues
  __shared__ __align__(16) u16 As[BMv * 64];
  __shared__ __align__(16) u16 Bs[128 * 64];
  const int bn = blockIdx.x * 128, bm = blockIdx.y * BMv;
  const int tid = threadIdx.x, lane = tid & 63, wid = tid >> 6;
  const int g = lane >> 4, fl = lane & 15;
  const int wm = wid >> 1, wn = wid & 1;

  const u16* ag = A + (size_t)(bm + wid * 8 + (lane >> 3)) * K + ((lane & 7) << 3);
  const u16* bg = BT + (size_t)(bn + wid * 8 + (lane >> 3)) * K + ((lane & 7) << 3);
  u16* al = As + wid * 512;
  u16* bl = Bs + wid * 512;

  f32x4 acc[MI][4] = {};

  for (int kk = 0; kk < K; kk += 64) {
#pragma unroll
    for (int is = 0; is < MI; ++is)
      gload16(ag + kk + (size_t)is * 32 * K, al + is * 2048);
#pragma unroll
    for (int is = 0; is < 4; ++is)
      gload16(bg + kk + (size_t)is * 32 * K, bl + is * 2048);
    __syncthreads();
#pragma unroll
    for (int k0 = 0; k0 < 64; k0 += 32) {
      short8 af[MI], bf[4];
#pragma unroll
      for (int i = 0; i < MI; ++i) {
        const u16* p = As + (wm * (BMv / 2) + i * 16 + fl) * 64 + k0 + 4 * g;
        af[i] = mk8(*(const us4*)p, *(const us4*)(p + 16));
      }
#pragma unroll
      for (int j = 0; j < 4; ++j) {
        const u16* p = Bs + (wn * 64 + j * 16 + fl) * 64 + k0 + 4 * g;
        bf[j] = mk8(*(const us4*)p, *(const us4*)(p + 16));
      }
#pragma unroll
      for (int i = 0; i < MI; ++i)
#pragma unroll
        for (int j = 0; j < 4; ++j)
          acc[i][j] = __builtin_amdgcn_mfma_f32_16x16x32_bf16(af[i], bf[j], acc[i][j], 0, 0, 0);
    }
    __syncthreads();
  }

  const int row0 = bm + wm * (BMv / 2) + 4 * g;
  const int col0 = bn + wn * 64 + fl;
#pragma unroll
  for (int j = 0; j < 4; ++j) {
    int col = col0 + j * 16;
    float bv = (EP == 3) ? 0.0f : bias[col];
#pragma unroll
    for (int i = 0; i < MI; ++i) {
#pragma unroll
      for (int r = 0; r < 4; ++r) {
        int row = row0 + i * 16 + r;
        float val = acc[i][j][r] + bv;
        size_t idx = (size_t)row * N + col;
        if (EP == 0) {
          ((u16*)outp)[idx] = f2bf(val);
        } else if (EP == 1) {
          ((float*)outp)[idx] += val;
        } else if (EP == 2) {
          float t = 0.7978845608028654f * (val + 0.044715f * val * val * val);
          ((u16*)outp)[idx] = f2bf(0.5f * val * (1.0f + tanhf(t)));
        } else {
          ((float*)outp)[idx] = val;
        }
      }
    }
  }
}

// ---------------- flash attention (reads fused qkv, stride 2304) ----------------
__global__ __launch_bounds__(256) void k_attn(const u16* __restrict__ qkv,
                                              u16* __restrict__ O) {
  __shared__ u16 Vt[DHEAD * 68];   // transposed V tile: Vt[d][key(64)]
  const int qb = blockIdx.x;
  const int bh = blockIdx.y;
  const int b = bh / NH, hh = bh % NH;
  const int tid = threadIdx.x, lane = tid & 63, w = tid >> 6;
  const int g = lane >> 4, fl = lane & 15;
  const int qrow = qb * 64 + w * 16 + fl;
  const u16* qp = qkv + (size_t)(b * SEQ + qrow) * NQKV + hh * DHEAD;

  short8 qf[2];
#pragma unroll
  for (int hf = 0; hf < 2; ++hf) {
    us4 lo = *(const us4*)(qp + hf * 32 + 4 * g);
    us4 hi = *(const us4*)(qp + hf * 32 + 16 + 4 * g);
    qf[hf] = mk8(lo, hi);
  }

  float m = -1e30f, lsum = 0.0f;
  f32x4 oacc[4] = {};
  const int qmaxw = qb * 64 + w * 16 + 15;
  const int vr = tid >> 2, vd = (tid & 3) << 4;

  for (int t64 = 0; t64 <= qb; ++t64) {
    const u16* vp = qkv + (size_t)(b * SEQ + t64 * 64 + vr) * NQKV + 2 * DMODEL + hh * DHEAD + vd;
#pragma unroll
    for (int qi = 0; qi < 4; ++qi) {
      us4 vv = *(const us4*)(vp + qi * 4);
#pragma unroll
      for (int i = 0; i < 4; ++i) Vt[(vd + qi * 4 + i) * 68 + vr] = vv[i];
    }
    __syncthreads();

#pragma unroll
    for (int i32 = 0; i32 < 2; ++i32) {
      int kb = t64 * 64 + i32 * 32;
      if (kb <= qmaxw) {
        f32x4 sfr[2];
#pragma unroll
        for (int sub = 0; sub < 2; ++sub) {
          const u16* kp = qkv + (size_t)(b * SEQ + kb + sub * 16 + fl) * NQKV + DMODEL + hh * DHEAD;
          short8 kf0 = mk8(*(const us4*)(kp + 4 * g), *(const us4*)(kp + 16 + 4 * g));
          short8 kf1 = mk8(*(const us4*)(kp + 32 + 4 * g), *(const us4*)(kp + 48 + 4 * g));
          f32x4 s = {};
          s = __builtin_amdgcn_mfma_f32_16x16x32_bf16(kf0, qf[0], s, 0, 0, 0);
          s = __builtin_amdgcn_mfma_f32_16x16x32_bf16(kf1, qf[1], s, 0, 0, 0);
          sfr[sub] = s;
        }
        float sc[8];
#pragma unroll
        for (int sub = 0; sub < 2; ++sub)
#pragma unroll
          for (int r = 0; r < 4; ++r) {
            int key = kb + sub * 16 + 4 * g + r;
            float sv = sfr[sub][r] * 0.125f;
            sc[sub * 4 + r] = (key <= qrow) ? sv : -1e30f;
          }
        float pmax = sc[0];
#pragma unroll
        for (int e = 1; e < 8; ++e) pmax = fmaxf(pmax, sc[e]);
        pmax = fmaxf(pmax, __shfl_xor(pmax, 16));
        pmax = fmaxf(pmax, __shfl_xor(pmax, 32));
        float mnew = fmaxf(m, pmax);
        float corr = __expf(m - mnew);
        float p[8], ps = 0.0f;
#pragma unroll
        for (int e = 0; e < 8; ++e) { p[e] = __expf(sc[e] - mnew); ps += p[e]; }
        ps += __shfl_xor(ps, 16);
        ps += __shfl_xor(ps, 32);
        lsum = lsum * corr + ps;
        m = mnew;
        float cr[4];
#pragma unroll
        for (int r = 0; r < 4; ++r) cr[r] = __shfl(corr, 4 * g + r);
#pragma unroll
        for (int nb = 0; nb < 4; ++nb)
#pragma unroll
          for (int r = 0; r < 4; ++r) oacc[nb][r] *= cr[r];
        short8 pf;
#pragma unroll
        for (int e = 0; e < 8; ++e) pf[e] = (short)f2bf(p[e]);
#pragma unroll
        for (int nb = 0; nb < 4; ++nb) {
          const u16* vtp = Vt + (nb * 16 + fl) * 68 + i32 * 32 + 4 * g;
          short8 vf = mk8(*(const us4*)vtp, *(const us4*)(vtp + 16));
          oacc[nb] = __builtin_amdgcn_mfma_f32_16x16x32_bf16(pf, vf, oacc[nb], 0, 0, 0);
        }
      }
    }
    __syncthreads();
  }

  float lr[4];
#pragma unroll
  for (int r = 0; r < 4; ++r) lr[r] = __shfl(lsum, 4 * g + r);
  const int orow0 = b * SEQ + qb * 64 + w * 16 + 4 * g;
#pragma unroll
  for (int nb = 0; nb < 4; ++nb) {
    int col = hh * DHEAD + nb * 16 + fl;
#pragma unroll
    for (int r = 0; r < 4; ++r)
      O[(size_t)(orow0 + r) * DMODEL + col] = f2bf(oacc[nb][r] / lr[r]);
  }
}

// ---------------- launcher ----------------
extern "C" void kernel_launch(void* const* d_in, const int* in_sizes, int n_in,
                              void* d_out, int out_size, void* d_ws, size_t ws_size,
                              hipStream_t stream) {
  const int*   x    = (const int*)d_in[0];
  const float* emb  = (const float*)d_in[1];
  const float* pos  = (const float*)d_in[2];
  const float* ln1g = (const float*)d_in[3];
  const float* ln1b = (const float*)d_in[4];
  const float* wq   = (const float*)d_in[5];
  const float* bq   = (const float*)d_in[6];
  const float* wk   = (const float*)d_in[7];
  const float* bk   = (const float*)d_in[8];
  const float* wv   = (const float*)d_in[9];
  const float* bv   = (const float*)d_in[10];
  const float* wo   = (const float*)d_in[11];
  const float* bo   = (const float*)d_in[12];
  const float* ln2g = (const float*)d_in[13];
  const float* ln2b = (const float*)d_in[14];
  const float* win  = (const float*)d_in[15];
  const float* bin  = (const float*)d_in[16];
  const float* wout = (const float*)d_in[17];
  const float* bout = (const float*)d_in[18];
  const float* lnfg = (const float*)d_in[19];
  const float* lnfb = (const float*)d_in[20];
  const float* outw = (const float*)d_in[21];

  char* w8 = (char*)d_ws;
  float* h    = (float*)(w8);                 // 6291456
  u16* abuf   = (u16*)(w8 + 6291456);         // 3145728
  u16* qkv    = (u16*)(w8 + 9437184);         // 9437184 (2048*2304*2)
  u16* obuf   = (u16*)(w8 + 18874368);        // 3145728
  u16* ffbuf  = (u16*)(w8 + 9437184);         // alias qkv+obuf (12582912)
  u16* wqkvT  = (u16*)(w8 + 22020096);        // 3538944
  u16* woT    = (u16*)(w8 + 25559040);        // 1179648
  u16* winT   = (u16*)(w8 + 26738688);        // 4718592
  u16* woutT  = (u16*)(w8 + 31457280);        // 4718592
  u16* outwT  = (u16*)(w8 + 36175872);        // 786432
  float* bqkv = (float*)(w8 + 36962304);      // 36864   (end ~35.3 MB)

  k_embed<<<TKN, 256, 0, stream>>>(x, emb, pos, h);
  k_packb<<<36, 256, 0, stream>>>(bq, bk, bv, bqkv);
  k_cvtT<<<dim3(12, 8), 256, 0, stream>>>(outw, outwT, DMODEL, NVOCAB);

  for (int l = 0; l < NL; ++l) {
    k_cvtQKV<<<dim3(12, 36), 256, 0, stream>>>(
        wq + (size_t)l * DMODEL * DMODEL, wk + (size_t)l * DMODEL * DMODEL,
        wv + (size_t)l * DMODEL * DMODEL, wqkvT);
    k_cvtT<<<dim3(12, 12), 256, 0, stream>>>(wo + (size_t)l * DMODEL * DMODEL, woT, DMODEL, DMODEL);
    k_cvtT<<<dim3(12, 48), 256, 0, stream>>>(win + (size_t)l * DMODEL * DFF, winT, DMODEL, DFF);
    k_cvtT<<<dim3(48, 12), 256, 0, stream>>>(wout + (size_t)l * DFF * DMODEL, woutT, DFF, DMODEL);

    k_ln<<<TKN, 256, 0, stream>>>(h, ln1g + l * DMODEL, ln1b + l * DMODEL, abuf);
    k_mm<0, 128><<<dim3(NQKV / 128, TKN / 128), 256, 0, stream>>>(
        abuf, wqkvT, bqkv + l * NQKV, qkv, NQKV, DMODEL);
    k_attn<<<dim3(SEQ / 64, 2 * NH), 256, 0, stream>>>(qkv, obuf);
    k_mm<1, 64><<<dim3(DMODEL / 128, TKN / 64), 256, 0, stream>>>(
        obuf, woT, bo + l * DMODEL, h, DMODEL, DMODEL);
    k_ln<<<TKN, 256, 0, stream>>>(h, ln2g + l * DMODEL, ln2b + l * DMODEL, abuf);
    k_mm<2, 128><<<dim3(DFF / 128, TKN / 128), 256, 0, stream>>>(
        abuf, winT, bin + l * DFF, ffbuf, DFF, DMODEL);
    k_mm<1, 64><<<dim3(DMODEL / 128, TKN / 64), 256, 0, stream>>>(
        ffbuf, woutT, bout + l * DMODEL, h, DMODEL, DFF);
  }

  k_ln<<<TKN, 256, 0, stream>>>(h, lnfg, lnfb, abuf);
  k_mm<3, 64><<<dim3(NVOCAB / 128, TKN / 64), 256, 0, stream>>>(
      abuf, outwT, nullptr, d_out, NVOCAB, DMODEL);
}

// Round 4
// 897.131 us; speedup vs baseline: 2.2440x; 2.2440x over previous
//
#include <hip/hip_runtime.h>
#include <hip/hip_bf16.h>

// GPT forward: L=4, B=2, S=1024, D=768, H=12, DK=64, DI=3072, V=512
// R4: + LDS XOR-swizzle (T2, via pre-swizzled global src for global_load_lds),
//     + double-buffered 2-phase prefetch K-loop (T3 minimum),
//     + bijective XCD chunk swizzle (T1).

#define TKN    2048
#define DMODEL 768
#define SEQ    1024
#define NH     12
#define DHEAD  64
#define DFF    3072
#define NL     4
#define NVOCAB 512
#define NQKV   2304   // 3*DMODEL

typedef unsigned short u16;
typedef __attribute__((ext_vector_type(4))) float f32x4;
typedef __attribute__((ext_vector_type(8))) short short8;
typedef __attribute__((ext_vector_type(4))) unsigned short us4;

__device__ __forceinline__ u16 f2bf(float f) {
  unsigned u = __builtin_bit_cast(unsigned, f);
  u += 0x7fffu + ((u >> 16) & 1u);   // RNE
  return (u16)(u >> 16);
}

__device__ __forceinline__ short8 mk8(us4 lo, us4 hi) {
  short8 r;
  r[0] = (short)lo[0]; r[1] = (short)lo[1]; r[2] = (short)lo[2]; r[3] = (short)lo[3];
  r[4] = (short)hi[0]; r[5] = (short)hi[1]; r[6] = (short)hi[2]; r[7] = (short)hi[3];
  return r;
}

// async global->LDS, 16B per lane; LDS dest = wave-uniform base + lane*16
__device__ __forceinline__ void gload16(const u16* g, u16* l) {
  __builtin_amdgcn_global_load_lds(
      (const __attribute__((address_space(1))) unsigned int*)g,
      (__attribute__((address_space(3))) unsigned int*)l, 16, 0, 0);
}

// ---------------- embedding ----------------
__global__ __launch_bounds__(256) void k_embed(const int* __restrict__ x,
                                               const float* __restrict__ emb,
                                               const float* __restrict__ pos,
                                               float* __restrict__ h) {
  int t = blockIdx.x;
  int s = t & (SEQ - 1);
  int id = x[t];
  int d = threadIdx.x;
#pragma unroll
  for (int j = 0; j < 3; ++j, d += 256)
    h[t * DMODEL + d] = emb[id * DMODEL + d] + pos[s * DMODEL + d];
}

// ---------------- layernorm (f32 in -> bf16 out) ----------------
__global__ __launch_bounds__(256) void k_ln(const float* __restrict__ h,
                                            const float* __restrict__ gam,
                                            const float* __restrict__ bet,
                                            u16* __restrict__ out) {
  __shared__ float sbuf[8];
  int row = blockIdx.x, tid = threadIdx.x;
  const float* hr = h + (size_t)row * DMODEL;
  float x0 = hr[tid], x1 = hr[tid + 256], x2 = hr[tid + 512];
  float s = x0 + x1 + x2;
#pragma unroll
  for (int off = 32; off > 0; off >>= 1) s += __shfl_down(s, off);
  if ((tid & 63) == 0) sbuf[tid >> 6] = s;
  __syncthreads();
  float mu = (sbuf[0] + sbuf[1] + sbuf[2] + sbuf[3]) * (1.0f / DMODEL);
  float d0 = x0 - mu, d1 = x1 - mu, d2 = x2 - mu;
  float v = d0 * d0 + d1 * d1 + d2 * d2;
#pragma unroll
  for (int off = 32; off > 0; off >>= 1) v += __shfl_down(v, off);
  if ((tid & 63) == 0) sbuf[4 + (tid >> 6)] = v;
  __syncthreads();
  float var = (sbuf[4] + sbuf[5] + sbuf[6] + sbuf[7]) * (1.0f / DMODEL);
  float rstd = rsqrtf(var + 1e-5f);
  size_t o = (size_t)row * DMODEL;
  out[o + tid]       = f2bf(d0 * rstd * gam[tid]       + bet[tid]);
  out[o + tid + 256] = f2bf(d1 * rstd * gam[tid + 256] + bet[tid + 256]);
  out[o + tid + 512] = f2bf(d2 * rstd * gam[tid + 512] + bet[tid + 512]);
}

// ---------------- weight convert+transpose: dst[n][k] = bf16(src[k][n]) ----------------
__global__ __launch_bounds__(256) void k_cvtT(const float* __restrict__ src,
                                              u16* __restrict__ dst,
                                              int K, int N) {
  __shared__ u16 tl[64][72];
  int k0 = blockIdx.x * 64, n0 = blockIdx.y * 64;
  int t = threadIdx.x;
  int kr = t >> 2, nj = (t & 3) << 4;
  const float* sp = src + (size_t)(k0 + kr) * N + n0 + nj;
  float4 a0 = ((const float4*)sp)[0];
  float4 a1 = ((const float4*)sp)[1];
  float4 a2 = ((const float4*)sp)[2];
  float4 a3 = ((const float4*)sp)[3];
  u16* tr = &tl[kr][nj];
  tr[0]=f2bf(a0.x); tr[1]=f2bf(a0.y); tr[2]=f2bf(a0.z); tr[3]=f2bf(a0.w);
  tr[4]=f2bf(a1.x); tr[5]=f2bf(a1.y); tr[6]=f2bf(a1.z); tr[7]=f2bf(a1.w);
  tr[8]=f2bf(a2.x); tr[9]=f2bf(a2.y); tr[10]=f2bf(a2.z); tr[11]=f2bf(a2.w);
  tr[12]=f2bf(a3.x); tr[13]=f2bf(a3.y); tr[14]=f2bf(a3.z); tr[15]=f2bf(a3.w);
  __syncthreads();
  int nr = t >> 2, kj = (t & 3) << 4;
  us4 o[4];
#pragma unroll
  for (int c = 0; c < 4; ++c)
#pragma unroll
    for (int i = 0; i < 4; ++i) o[c][i] = tl[kj + c * 4 + i][nr];
  u16* dp = dst + (size_t)(n0 + nr) * K + k0 + kj;
  ((us4*)dp)[0] = o[0]; ((us4*)dp)[1] = o[1];
  ((us4*)dp)[2] = o[2]; ((us4*)dp)[3] = o[3];
}

// fused QKV weight convert: dst[2304][768]
__global__ __launch_bounds__(256) void k_cvtQKV(const float* __restrict__ wq,
                                                const float* __restrict__ wk,
                                                const float* __restrict__ wv,
                                                u16* __restrict__ dst) {
  __shared__ u16 tl[64][72];
  int k0 = blockIdx.x * 64, gn0 = blockIdx.y * 64;
  int sel = gn0 / DMODEL;
  int n0 = gn0 - sel * DMODEL;
  const float* src = sel == 0 ? wq : sel == 1 ? wk : wv;
  int t = threadIdx.x;
  int kr = t >> 2, nj = (t & 3) << 4;
  const float* sp = src + (size_t)(k0 + kr) * DMODEL + n0 + nj;
  float4 a0 = ((const float4*)sp)[0];
  float4 a1 = ((const float4*)sp)[1];
  float4 a2 = ((const float4*)sp)[2];
  float4 a3 = ((const float4*)sp)[3];
  u16* tr = &tl[kr][nj];
  tr[0]=f2bf(a0.x); tr[1]=f2bf(a0.y); tr[2]=f2bf(a0.z); tr[3]=f2bf(a0.w);
  tr[4]=f2bf(a1.x); tr[5]=f2bf(a1.y); tr[6]=f2bf(a1.z); tr[7]=f2bf(a1.w);
  tr[8]=f2bf(a2.x); tr[9]=f2bf(a2.y); tr[10]=f2bf(a2.z); tr[11]=f2bf(a2.w);
  tr[12]=f2bf(a3.x); tr[13]=f2bf(a3.y); tr[14]=f2bf(a3.z); tr[15]=f2bf(a3.w);
  __syncthreads();
  int nr = t >> 2, kj = (t & 3) << 4;
  us4 o[4];
#pragma unroll
  for (int c = 0; c < 4; ++c)
#pragma unroll
    for (int i = 0; i < 4; ++i) o[c][i] = tl[kj + c * 4 + i][nr];
  u16* dp = dst + (size_t)(gn0 + nr) * DMODEL + k0 + kj;
  ((us4*)dp)[0] = o[0]; ((us4*)dp)[1] = o[1];
  ((us4*)dp)[2] = o[2]; ((us4*)dp)[3] = o[3];
}

// pack fused QKV bias
__global__ __launch_bounds__(256) void k_packb(const float* __restrict__ bq,
                                               const float* __restrict__ bk,
                                               const float* __restrict__ bv,
                                               float* __restrict__ dst) {
  int i = blockIdx.x * 256 + threadIdx.x;
  if (i < NL * NQKV) {
    int l = i / NQKV, j = i - l * NQKV;
    float v = j < DMODEL ? bq[l * DMODEL + j]
            : j < 2 * DMODEL ? bk[l * DMODEL + j - DMODEL]
            : bv[l * DMODEL + j - 2 * DMODEL];
    dst[i] = v;
  }
}

// ---------------- GEMM: C[M,N] = A[M,K](bf16) * BT[N,K](bf16) ----------------
// EP 0: bf16 = acc+bias   EP 1: f32 += acc+bias   EP 2: bf16 = gelu(acc+bias)
// EP 3: f32 = acc
// BMv x 128 tile, BK=64, 4 waves. LDS XOR-swizzled ((row&7)<<4 on byte addr),
// double-buffered with prefetch-before-compute.
template <int EP, int BMv>
__global__ __launch_bounds__(256) void k_mm(const u16* __restrict__ A,
                                            const u16* __restrict__ BT,
                                            const float* __restrict__ bias,
                                            void* __restrict__ outp,
                                            int N, int K) {
  constexpr int MI = BMv / 32;
  __shared__ __align__(16) u16 As[2][BMv * 64];
  __shared__ __align__(16) u16 Bs[2][128 * 64];
  // bijective XCD chunk swizzle (all grids are multiples of 8 blocks)
  const int nbx = gridDim.x;
  int lin = blockIdx.y * nbx + blockIdx.x;
  const int chunk = (nbx * gridDim.y) >> 3;
  lin = (lin & 7) * chunk + (lin >> 3);
  const int bn = (lin % nbx) * 128, bm = (lin / nbx) * BMv;

  const int tid = threadIdx.x, lane = tid & 63, wid = tid >> 6;
  const int g = lane >> 4, fl = lane & 15;
  const int wm = wid >> 1, wn = wid & 1;

  // staging: row (within 32-row group) = wid*8 + lane>>3; source col pre-swizzled
  const int srow = wid * 8 + (lane >> 3);
  const int scol = ((lane & 7) ^ (lane >> 3)) << 3;   // elems
  const u16* ag = A + (size_t)(bm + srow) * K + scol;
  const u16* bg = BT + (size_t)(bn + srow) * K + scol;

  f32x4 acc[MI][4] = {};
  const int sw = (fl & 7) << 4;   // read-side swizzle (byte)

  auto stage = [&](int buf, int kk) {
#pragma unroll
    for (int is = 0; is < MI; ++is)
      gload16(ag + kk + (size_t)is * 32 * K, &As[buf][wid * 512 + is * 2048]);
#pragma unroll
    for (int is = 0; is < 4; ++is)
      gload16(bg + kk + (size_t)is * 32 * K, &Bs[buf][wid * 512 + is * 2048]);
  };

  const int nk = K >> 6;
  stage(0, 0);
  __syncthreads();
  int cur = 0;
  for (int kt = 0; kt < nk; ++kt) {
    if (kt + 1 < nk) stage(cur ^ 1, (kt + 1) << 6);
#pragma unroll
    for (int k0 = 0; k0 < 64; k0 += 32) {
      const int bo = (k0 + 4 * g) * 2;
      short8 af[MI], bf[4];
#pragma unroll
      for (int i = 0; i < MI; ++i) {
        const char* base = (const char*)&As[cur][(wm * (BMv / 2) + i * 16 + fl) * 64];
        af[i] = mk8(*(const us4*)(base + (bo ^ sw)),
                    *(const us4*)(base + ((bo + 32) ^ sw)));
      }
#pragma unroll
      for (int j = 0; j < 4; ++j) {
        const char* base = (const char*)&Bs[cur][(wn * 64 + j * 16 + fl) * 64];
        bf[j] = mk8(*(const us4*)(base + (bo ^ sw)),
                    *(const us4*)(base + ((bo + 32) ^ sw)));
      }
#pragma unroll
      for (int i = 0; i < MI; ++i)
#pragma unroll
        for (int j = 0; j < 4; ++j)
          acc[i][j] = __builtin_amdgcn_mfma_f32_16x16x32_bf16(af[i], bf[j], acc[i][j], 0, 0, 0);
    }
    __syncthreads();
    cur ^= 1;
  }

  const int row0 = bm + wm * (BMv / 2) + 4 * g;
  const int col0 = bn + wn * 64 + fl;
#pragma unroll
  for (int j = 0; j < 4; ++j) {
    int col = col0 + j * 16;
    float bv = (EP == 3) ? 0.0f : bias[col];
#pragma unroll
    for (int i = 0; i < MI; ++i) {
#pragma unroll
      for (int r = 0; r < 4; ++r) {
        int row = row0 + i * 16 + r;
        float val = acc[i][j][r] + bv;
        size_t idx = (size_t)row * N + col;
        if (EP == 0) {
          ((u16*)outp)[idx] = f2bf(val);
        } else if (EP == 1) {
          ((float*)outp)[idx] += val;
        } else if (EP == 2) {
          float t = 0.7978845608028654f * (val + 0.044715f * val * val * val);
          ((u16*)outp)[idx] = f2bf(0.5f * val * (1.0f + tanhf(t)));
        } else {
          ((float*)outp)[idx] = val;
        }
      }
    }
  }
}

// ---------------- flash attention (reads fused qkv, stride 2304) ----------------
__global__ __launch_bounds__(256) void k_attn(const u16* __restrict__ qkv,
                                              u16* __restrict__ O) {
  __shared__ u16 Vt[DHEAD * 68];
  // XCD chunk swizzle: grid 16 x 24 = 384 blocks
  int lin = blockIdx.y * gridDim.x + blockIdx.x;
  const int chunk = (gridDim.x * gridDim.y) >> 3;
  lin = (lin & 7) * chunk + (lin >> 3);
  const int qb = lin % gridDim.x;
  const int bh = lin / gridDim.x;
  const int b = bh / NH, hh = bh % NH;
  const int tid = threadIdx.x, lane = tid & 63, w = tid >> 6;
  const int g = lane >> 4, fl = lane & 15;
  const int qrow = qb * 64 + w * 16 + fl;
  const u16* qp = qkv + (size_t)(b * SEQ + qrow) * NQKV + hh * DHEAD;

  short8 qf[2];
#pragma unroll
  for (int hf = 0; hf < 2; ++hf) {
    us4 lo = *(const us4*)(qp + hf * 32 + 4 * g);
    us4 hi = *(const us4*)(qp + hf * 32 + 16 + 4 * g);
    qf[hf] = mk8(lo, hi);
  }

  float m = -1e30f, lsum = 0.0f;
  f32x4 oacc[4] = {};
  const int qmaxw = qb * 64 + w * 16 + 15;
  const int vr = tid >> 2, vd = (tid & 3) << 4;

  for (int t64 = 0; t64 <= qb; ++t64) {
    const u16* vp = qkv + (size_t)(b * SEQ + t64 * 64 + vr) * NQKV + 2 * DMODEL + hh * DHEAD + vd;
#pragma unroll
    for (int qi = 0; qi < 4; ++qi) {
      us4 vv = *(const us4*)(vp + qi * 4);
#pragma unroll
      for (int i = 0; i < 4; ++i) Vt[(vd + qi * 4 + i) * 68 + vr] = vv[i];
    }
    __syncthreads();

#pragma unroll
    for (int i32 = 0; i32 < 2; ++i32) {
      int kb = t64 * 64 + i32 * 32;
      if (kb <= qmaxw) {
        f32x4 sfr[2];
#pragma unroll
        for (int sub = 0; sub < 2; ++sub) {
          const u16* kp = qkv + (size_t)(b * SEQ + kb + sub * 16 + fl) * NQKV + DMODEL + hh * DHEAD;
          short8 kf0 = mk8(*(const us4*)(kp + 4 * g), *(const us4*)(kp + 16 + 4 * g));
          short8 kf1 = mk8(*(const us4*)(kp + 32 + 4 * g), *(const us4*)(kp + 48 + 4 * g));
          f32x4 s = {};
          s = __builtin_amdgcn_mfma_f32_16x16x32_bf16(kf0, qf[0], s, 0, 0, 0);
          s = __builtin_amdgcn_mfma_f32_16x16x32_bf16(kf1, qf[1], s, 0, 0, 0);
          sfr[sub] = s;
        }
        float sc[8];
#pragma unroll
        for (int sub = 0; sub < 2; ++sub)
#pragma unroll
          for (int r = 0; r < 4; ++r) {
            int key = kb + sub * 16 + 4 * g + r;
            float sv = sfr[sub][r] * 0.125f;
            sc[sub * 4 + r] = (key <= qrow) ? sv : -1e30f;
          }
        float pmax = sc[0];
#pragma unroll
        for (int e = 1; e < 8; ++e) pmax = fmaxf(pmax, sc[e]);
        pmax = fmaxf(pmax, __shfl_xor(pmax, 16));
        pmax = fmaxf(pmax, __shfl_xor(pmax, 32));
        float mnew = fmaxf(m, pmax);
        float corr = __expf(m - mnew);
        float p[8], ps = 0.0f;
#pragma unroll
        for (int e = 0; e < 8; ++e) { p[e] = __expf(sc[e] - mnew); ps += p[e]; }
        ps += __shfl_xor(ps, 16);
        ps += __shfl_xor(ps, 32);
        lsum = lsum * corr + ps;
        m = mnew;
        float cr[4];
#pragma unroll
        for (int r = 0; r < 4; ++r) cr[r] = __shfl(corr, 4 * g + r);
#pragma unroll
        for (int nb = 0; nb < 4; ++nb)
#pragma unroll
          for (int r = 0; r < 4; ++r) oacc[nb][r] *= cr[r];
        short8 pf;
#pragma unroll
        for (int e = 0; e < 8; ++e) pf[e] = (short)f2bf(p[e]);
#pragma unroll
        for (int nb = 0; nb < 4; ++nb) {
          const u16* vtp = Vt + (nb * 16 + fl) * 68 + i32 * 32 + 4 * g;
          short8 vf = mk8(*(const us4*)vtp, *(const us4*)(vtp + 16));
          oacc[nb] = __builtin_amdgcn_mfma_f32_16x16x32_bf16(pf, vf, oacc[nb], 0, 0, 0);
        }
      }
    }
    __syncthreads();
  }

  float lr[4];
#pragma unroll
  for (int r = 0; r < 4; ++r) lr[r] = __shfl(lsum, 4 * g + r);
  const int orow0 = b * SEQ + qb * 64 + w * 16 + 4 * g;
#pragma unroll
  for (int nb = 0; nb < 4; ++nb) {
    int col = hh * DHEAD + nb * 16 + fl;
#pragma unroll
    for (int r = 0; r < 4; ++r)
      O[(size_t)(orow0 + r) * DMODEL + col] = f2bf(oacc[nb][r] / lr[r]);
  }
}

// ---------------- launcher ----------------
extern "C" void kernel_launch(void* const* d_in, const int* in_sizes, int n_in,
                              void* d_out, int out_size, void* d_ws, size_t ws_size,
                              hipStream_t stream) {
  const int*   x    = (const int*)d_in[0];
  const float* emb  = (const float*)d_in[1];
  const float* pos  = (const float*)d_in[2];
  const float* ln1g = (const float*)d_in[3];
  const float* ln1b = (const float*)d_in[4];
  const float* wq   = (const float*)d_in[5];
  const float* bq   = (const float*)d_in[6];
  const float* wk   = (const float*)d_in[7];
  const float* bk   = (const float*)d_in[8];
  const float* wv   = (const float*)d_in[9];
  const float* bv   = (const float*)d_in[10];
  const float* wo   = (const float*)d_in[11];
  const float* bo   = (const float*)d_in[12];
  const float* ln2g = (const float*)d_in[13];
  const float* ln2b = (const float*)d_in[14];
  const float* win  = (const float*)d_in[15];
  const float* bin  = (const float*)d_in[16];
  const float* wout = (const float*)d_in[17];
  const float* bout = (const float*)d_in[18];
  const float* lnfg = (const float*)d_in[19];
  const float* lnfb = (const float*)d_in[20];
  const float* outw = (const float*)d_in[21];

  char* w8 = (char*)d_ws;
  float* h    = (float*)(w8);                 // 6291456
  u16* abuf   = (u16*)(w8 + 6291456);         // 3145728
  u16* qkv    = (u16*)(w8 + 9437184);         // 9437184
  u16* obuf   = (u16*)(w8 + 18874368);        // 3145728
  u16* ffbuf  = (u16*)(w8 + 9437184);         // alias qkv+obuf
  u16* wqkvT  = (u16*)(w8 + 22020096);        // 3538944
  u16* woT    = (u16*)(w8 + 25559040);        // 1179648
  u16* winT   = (u16*)(w8 + 26738688);        // 4718592
  u16* woutT  = (u16*)(w8 + 31457280);        // 4718592
  u16* outwT  = (u16*)(w8 + 36175872);        // 786432
  float* bqkv = (float*)(w8 + 36962304);      // 36864

  k_embed<<<TKN, 256, 0, stream>>>(x, emb, pos, h);
  k_packb<<<36, 256, 0, stream>>>(bq, bk, bv, bqkv);
  k_cvtT<<<dim3(12, 8), 256, 0, stream>>>(outw, outwT, DMODEL, NVOCAB);

  for (int l = 0; l < NL; ++l) {
    k_cvtQKV<<<dim3(12, 36), 256, 0, stream>>>(
        wq + (size_t)l * DMODEL * DMODEL, wk + (size_t)l * DMODEL * DMODEL,
        wv + (size_t)l * DMODEL * DMODEL, wqkvT);
    k_cvtT<<<dim3(12, 12), 256, 0, stream>>>(wo + (size_t)l * DMODEL * DMODEL, woT, DMODEL, DMODEL);
    k_cvtT<<<dim3(12, 48), 256, 0, stream>>>(win + (size_t)l * DMODEL * DFF, winT, DMODEL, DFF);
    k_cvtT<<<dim3(48, 12), 256, 0, stream>>>(wout + (size_t)l * DFF * DMODEL, woutT, DFF, DMODEL);

    k_ln<<<TKN, 256, 0, stream>>>(h, ln1g + l * DMODEL, ln1b + l * DMODEL, abuf);
    k_mm<0, 128><<<dim3(NQKV / 128, TKN / 128), 256, 0, stream>>>(
        abuf, wqkvT, bqkv + l * NQKV, qkv, NQKV, DMODEL);
    k_attn<<<dim3(SEQ / 64, 2 * NH), 256, 0, stream>>>(qkv, obuf);
    k_mm<1, 64><<<dim3(DMODEL / 128, TKN / 64), 256, 0, stream>>>(
        obuf, woT, bo + l * DMODEL, h, DMODEL, DMODEL);
    k_ln<<<TKN, 256, 0, stream>>>(h, ln2g + l * DMODEL, ln2b + l * DMODEL, abuf);
    k_mm<2, 128><<<dim3(DFF / 128, TKN / 128), 256, 0, stream>>>(
        abuf, winT, bin + l * DFF, ffbuf, DFF, DMODEL);
    k_mm<1, 64><<<dim3(DMODEL / 128, TKN / 64), 256, 0, stream>>>(
        ffbuf, woutT, bout + l * DMODEL, h, DMODEL, DFF);
  }

  k_ln<<<TKN, 256, 0, stream>>>(h, lnfg, lnfb, abuf);
  k_mm<3, 64><<<dim3(NVOCAB / 128, TKN / 64), 256, 0, stream>>>(
      abuf, outwT, nullptr, d_out, NVOCAB, DMODEL);
}

// Round 6
// 822.740 us; speedup vs baseline: 2.4469x; 1.0904x over previous
//
#include <hip/hip_runtime.h>
#include <hip/hip_bf16.h>

// GPT forward: L=4, B=2, S=1024, D=768, H=12, DK=64, DI=3072, V=512
// R6: R5 with the V-prefetch indexing compile fix (vv[qi][i]).

#define TKN    2048
#define DMODEL 768
#define SEQ    1024
#define NH     12
#define DHEAD  64
#define DFF    3072
#define NL     4
#define NVOCAB 512
#define NQKV   2304

typedef unsigned short u16;
typedef __attribute__((ext_vector_type(4))) float f32x4;
typedef __attribute__((ext_vector_type(8))) short short8;
typedef __attribute__((ext_vector_type(4))) unsigned short us4;

__device__ __forceinline__ u16 f2bf(float f) {
  unsigned u = __builtin_bit_cast(unsigned, f);
  u += 0x7fffu + ((u >> 16) & 1u);   // RNE
  return (u16)(u >> 16);
}

__device__ __forceinline__ short8 mk8(us4 lo, us4 hi) {
  short8 r;
  r[0] = (short)lo[0]; r[1] = (short)lo[1]; r[2] = (short)lo[2]; r[3] = (short)lo[3];
  r[4] = (short)hi[0]; r[5] = (short)hi[1]; r[6] = (short)hi[2]; r[7] = (short)hi[3];
  return r;
}

__device__ __forceinline__ void gload16(const u16* g, u16* l) {
  __builtin_amdgcn_global_load_lds(
      (const __attribute__((address_space(1))) unsigned int*)g,
      (__attribute__((address_space(3))) unsigned int*)l, 16, 0, 0);
}

// ---------------- embedding ----------------
__global__ __launch_bounds__(256) void k_embed(const int* __restrict__ x,
                                               const float* __restrict__ emb,
                                               const float* __restrict__ pos,
                                               float* __restrict__ h) {
  int t = blockIdx.x;
  int s = t & (SEQ - 1);
  int id = x[t];
  int d = threadIdx.x;
#pragma unroll
  for (int j = 0; j < 3; ++j, d += 256)
    h[t * DMODEL + d] = emb[id * DMODEL + d] + pos[s * DMODEL + d];
}

// ---------------- layernorm (f32 in -> bf16 out) ----------------
__global__ __launch_bounds__(256) void k_ln(const float* __restrict__ h,
                                            const float* __restrict__ gam,
                                            const float* __restrict__ bet,
                                            u16* __restrict__ out) {
  __shared__ float sbuf[8];
  int row = blockIdx.x, tid = threadIdx.x;
  const float* hr = h + (size_t)row * DMODEL;
  float x0 = hr[tid], x1 = hr[tid + 256], x2 = hr[tid + 512];
  float s = x0 + x1 + x2;
#pragma unroll
  for (int off = 32; off > 0; off >>= 1) s += __shfl_down(s, off);
  if ((tid & 63) == 0) sbuf[tid >> 6] = s;
  __syncthreads();
  float mu = (sbuf[0] + sbuf[1] + sbuf[2] + sbuf[3]) * (1.0f / DMODEL);
  float d0 = x0 - mu, d1 = x1 - mu, d2 = x2 - mu;
  float v = d0 * d0 + d1 * d1 + d2 * d2;
#pragma unroll
  for (int off = 32; off > 0; off >>= 1) v += __shfl_down(v, off);
  if ((tid & 63) == 0) sbuf[4 + (tid >> 6)] = v;
  __syncthreads();
  float var = (sbuf[4] + sbuf[5] + sbuf[6] + sbuf[7]) * (1.0f / DMODEL);
  float rstd = rsqrtf(var + 1e-5f);
  size_t o = (size_t)row * DMODEL;
  out[o + tid]       = f2bf(d0 * rstd * gam[tid]       + bet[tid]);
  out[o + tid + 256] = f2bf(d1 * rstd * gam[tid + 256] + bet[tid + 256]);
  out[o + tid + 512] = f2bf(d2 * rstd * gam[tid + 512] + bet[tid + 512]);
}

// ---------------- 64x64 transpose-convert tile ----------------
__device__ __forceinline__ void cvt_tile(const float* __restrict__ src, int ldS,
                                         int k0, int n0src,
                                         u16* __restrict__ dst, int ldD, int n0dst,
                                         int tid, u16 (*tl)[72]) {
  int kr = tid >> 2, nj = (tid & 3) << 4;
  const float* sp = src + (size_t)(k0 + kr) * ldS + n0src + nj;
  float4 a0 = ((const float4*)sp)[0];
  float4 a1 = ((const float4*)sp)[1];
  float4 a2 = ((const float4*)sp)[2];
  float4 a3 = ((const float4*)sp)[3];
  u16* tr = &tl[kr][nj];
  tr[0]=f2bf(a0.x); tr[1]=f2bf(a0.y); tr[2]=f2bf(a0.z); tr[3]=f2bf(a0.w);
  tr[4]=f2bf(a1.x); tr[5]=f2bf(a1.y); tr[6]=f2bf(a1.z); tr[7]=f2bf(a1.w);
  tr[8]=f2bf(a2.x); tr[9]=f2bf(a2.y); tr[10]=f2bf(a2.z); tr[11]=f2bf(a2.w);
  tr[12]=f2bf(a3.x); tr[13]=f2bf(a3.y); tr[14]=f2bf(a3.z); tr[15]=f2bf(a3.w);
  __syncthreads();
  int nr = tid >> 2, kj = (tid & 3) << 4;
  us4 o[4];
#pragma unroll
  for (int c = 0; c < 4; ++c)
#pragma unroll
    for (int i = 0; i < 4; ++i) o[c][i] = tl[kj + c * 4 + i][nr];
  u16* dp = dst + (size_t)(n0dst + nr) * ldD + k0 + kj;
  ((us4*)dp)[0] = o[0]; ((us4*)dp)[1] = o[1];
  ((us4*)dp)[2] = o[2]; ((us4*)dp)[3] = o[3];
}

// fused per-layer weight conversion: 1728 tiles
__global__ __launch_bounds__(256) void k_cvtL(const float* __restrict__ wq,
                                              const float* __restrict__ wk,
                                              const float* __restrict__ wv,
                                              const float* __restrict__ wo,
                                              const float* __restrict__ win,
                                              const float* __restrict__ wout,
                                              u16* __restrict__ wqkvT,
                                              u16* __restrict__ woT,
                                              u16* __restrict__ winT,
                                              u16* __restrict__ woutT) {
  __shared__ u16 tl[64][72];
  int t = blockIdx.x, tid = threadIdx.x;
  if (t < 432) {
    int kt = t % 12, ntile = t / 12;
    int gn0 = ntile * 64, sel = gn0 / DMODEL;
    const float* src = sel == 0 ? wq : sel == 1 ? wk : wv;
    cvt_tile(src, DMODEL, kt * 64, gn0 - sel * DMODEL, wqkvT, DMODEL, gn0, tid, tl);
  } else if (t < 576) {
    int t2 = t - 432, kt = t2 % 12, nt = t2 / 12;
    cvt_tile(wo, DMODEL, kt * 64, nt * 64, woT, DMODEL, nt * 64, tid, tl);
  } else if (t < 1152) {
    int t3 = t - 576, kt = t3 % 12, nt = t3 / 12;
    cvt_tile(win, DFF, kt * 64, nt * 64, winT, DMODEL, nt * 64, tid, tl);
  } else {
    int t4 = t - 1152, kt = t4 % 48, nt = t4 / 48;
    cvt_tile(wout, DMODEL, kt * 64, nt * 64, woutT, DFF, nt * 64, tid, tl);
  }
}

__global__ __launch_bounds__(256) void k_cvtT(const float* __restrict__ src,
                                              u16* __restrict__ dst,
                                              int K, int N) {
  __shared__ u16 tl[64][72];
  cvt_tile(src, N, blockIdx.x * 64, blockIdx.y * 64, dst, K, blockIdx.y * 64,
           threadIdx.x, tl);
}

__global__ __launch_bounds__(256) void k_packb(const float* __restrict__ bq,
                                               const float* __restrict__ bk,
                                               const float* __restrict__ bv,
                                               float* __restrict__ dst) {
  int i = blockIdx.x * 256 + threadIdx.x;
  if (i < NL * NQKV) {
    int l = i / NQKV, j = i - l * NQKV;
    float v = j < DMODEL ? bq[l * DMODEL + j]
            : j < 2 * DMODEL ? bk[l * DMODEL + j - DMODEL]
            : bv[l * DMODEL + j - 2 * DMODEL];
    dst[i] = v;
  }
}

// ---------------- GEMM (unchanged from R4) ----------------
template <int EP, int BMv>
__global__ __launch_bounds__(256) void k_mm(const u16* __restrict__ A,
                                            const u16* __restrict__ BT,
                                            const float* __restrict__ bias,
                                            void* __restrict__ outp,
                                            int N, int K) {
  constexpr int MI = BMv / 32;
  __shared__ __align__(16) u16 As[2][BMv * 64];
  __shared__ __align__(16) u16 Bs[2][128 * 64];
  const int nbx = gridDim.x;
  int lin = blockIdx.y * nbx + blockIdx.x;
  const int chunk = (nbx * gridDim.y) >> 3;
  lin = (lin & 7) * chunk + (lin >> 3);
  const int bn = (lin % nbx) * 128, bm = (lin / nbx) * BMv;

  const int tid = threadIdx.x, lane = tid & 63, wid = tid >> 6;
  const int g = lane >> 4, fl = lane & 15;
  const int wm = wid >> 1, wn = wid & 1;

  const int srow = wid * 8 + (lane >> 3);
  const int scol = ((lane & 7) ^ (lane >> 3)) << 3;
  const u16* ag = A + (size_t)(bm + srow) * K + scol;
  const u16* bg = BT + (size_t)(bn + srow) * K + scol;

  f32x4 acc[MI][4] = {};
  const int sw = (fl & 7) << 4;

  auto stage = [&](int buf, int kk) {
#pragma unroll
    for (int is = 0; is < MI; ++is)
      gload16(ag + kk + (size_t)is * 32 * K, &As[buf][wid * 512 + is * 2048]);
#pragma unroll
    for (int is = 0; is < 4; ++is)
      gload16(bg + kk + (size_t)is * 32 * K, &Bs[buf][wid * 512 + is * 2048]);
  };

  const int nk = K >> 6;
  stage(0, 0);
  __syncthreads();
  int cur = 0;
  for (int kt = 0; kt < nk; ++kt) {
    if (kt + 1 < nk) stage(cur ^ 1, (kt + 1) << 6);
#pragma unroll
    for (int k0 = 0; k0 < 64; k0 += 32) {
      const int bo = (k0 + 4 * g) * 2;
      short8 af[MI], bf[4];
#pragma unroll
      for (int i = 0; i < MI; ++i) {
        const char* base = (const char*)&As[cur][(wm * (BMv / 2) + i * 16 + fl) * 64];
        af[i] = mk8(*(const us4*)(base + (bo ^ sw)),
                    *(const us4*)(base + ((bo + 32) ^ sw)));
      }
#pragma unroll
      for (int j = 0; j < 4; ++j) {
        const char* base = (const char*)&Bs[cur][(wn * 64 + j * 16 + fl) * 64];
        bf[j] = mk8(*(const us4*)(base + (bo ^ sw)),
                    *(const us4*)(base + ((bo + 32) ^ sw)));
      }
#pragma unroll
      for (int i = 0; i < MI; ++i)
#pragma unroll
        for (int j = 0; j < 4; ++j)
          acc[i][j] = __builtin_amdgcn_mfma_f32_16x16x32_bf16(af[i], bf[j], acc[i][j], 0, 0, 0);
    }
    __syncthreads();
    cur ^= 1;
  }

  const int row0 = bm + wm * (BMv / 2) + 4 * g;
  const int col0 = bn + wn * 64 + fl;
#pragma unroll
  for (int j = 0; j < 4; ++j) {
    int col = col0 + j * 16;
    float bv = (EP == 3) ? 0.0f : bias[col];
#pragma unroll
    for (int i = 0; i < MI; ++i) {
#pragma unroll
      for (int r = 0; r < 4; ++r) {
        int row = row0 + i * 16 + r;
        float val = acc[i][j][r] + bv;
        size_t idx = (size_t)row * N + col;
        if (EP == 0) {
          ((u16*)outp)[idx] = f2bf(val);
        } else if (EP == 1) {
          ((float*)outp)[idx] += val;
        } else if (EP == 2) {
          float t = 0.7978845608028654f * (val + 0.044715f * val * val * val);
          ((u16*)outp)[idx] = f2bf(0.5f * val * (1.0f + tanhf(t)));
        } else {
          ((float*)outp)[idx] = val;
        }
      }
    }
  }
}

// ---------------- flash attention, key-split partials ----------------
__global__ __launch_bounds__(256) void k_attn(const u16* __restrict__ qkv,
                                              float* __restrict__ pO,
                                              float* __restrict__ pML) {
  __shared__ u16 Vt[2][DHEAD * 68];
  int lin = blockIdx.y * gridDim.x + blockIdx.x;
  const int chunk = (gridDim.x * gridDim.y) >> 3;
  lin = (lin & 7) * chunk + (lin >> 3);
  const int qb = lin % gridDim.x;
  const int bh = lin / gridDim.x;
  const int sp = blockIdx.z;
  const int b = bh / NH, hh = bh % NH;
  const int tid = threadIdx.x, lane = tid & 63, w = tid >> 6;
  const int g = lane >> 4, fl = lane & 15;
  const int qrow = qb * 64 + w * 16 + fl;
  const u16* qp = qkv + (size_t)(b * SEQ + qrow) * NQKV + hh * DHEAD;

  short8 qf[2];
#pragma unroll
  for (int hf = 0; hf < 2; ++hf) {
    us4 lo = *(const us4*)(qp + hf * 32 + 4 * g);
    us4 hi = *(const us4*)(qp + hf * 32 + 16 + 4 * g);
    qf[hf] = mk8(lo, hi);
  }

  float m = -1e30f, lsum = 0.0f;
  f32x4 oacc[4] = {};
  const int qmaxw = qb * 64 + w * 16 + 15;
  const int vr = tid >> 2, vd = (tid & 3) << 4;
  const u16* vbase = qkv + (size_t)(b * SEQ + vr) * NQKV + 2 * DMODEL + hh * DHEAD + vd;
  const u16* kbase0 = qkv + (size_t)(b * SEQ) * NQKV + DMODEL + hh * DHEAD;

  const int nt = qb + 1;
  const int t_lo = (sp * nt) >> 1, t_hi = ((sp + 1) * nt) >> 1;

  if (t_lo < t_hi) {
    // prologue: stage V(t_lo) into Vt[0]
    {
      const u16* vp = vbase + (size_t)t_lo * 64 * NQKV;
      us4 vv[4];
#pragma unroll
      for (int qi = 0; qi < 4; ++qi) vv[qi] = *(const us4*)(vp + qi * 4);
#pragma unroll
      for (int qi = 0; qi < 4; ++qi)
#pragma unroll
        for (int i = 0; i < 4; ++i) Vt[0][(vd + qi * 4 + i) * 68 + vr] = vv[qi][i];
    }
    __syncthreads();
    int cur = 0;
    for (int t64 = t_lo; t64 < t_hi; ++t64) {
      // K prefetch: 4 key16-blocks x full 64-dim row
      const u16* kb64 = kbase0 + (size_t)t64 * 64 * NQKV;
      us4 kv[4][4];
#pragma unroll
      for (int q4 = 0; q4 < 4; ++q4) {
        const u16* kp = kb64 + (size_t)(q4 * 16 + fl) * NQKV;
#pragma unroll
        for (int j = 0; j < 4; ++j) kv[q4][j] = *(const us4*)(kp + j * 16 + 4 * g);
      }
      // V-next prefetch
      const bool pf = (t64 + 1 < t_hi);
      us4 vvn[4];
      if (pf) {
        const u16* vp = vbase + (size_t)(t64 + 1) * 64 * NQKV;
#pragma unroll
        for (int qi = 0; qi < 4; ++qi) vvn[qi] = *(const us4*)(vp + qi * 4);
      }

#pragma unroll
      for (int i32 = 0; i32 < 2; ++i32) {
        int kb = t64 * 64 + i32 * 32;
        if (kb <= qmaxw) {
          f32x4 sfr[2];
#pragma unroll
          for (int sub = 0; sub < 2; ++sub) {
            int q4 = i32 * 2 + sub;
            short8 kf0 = mk8(kv[q4][0], kv[q4][1]);
            short8 kf1 = mk8(kv[q4][2], kv[q4][3]);
            f32x4 s = {};
            s = __builtin_amdgcn_mfma_f32_16x16x32_bf16(kf0, qf[0], s, 0, 0, 0);
            s = __builtin_amdgcn_mfma_f32_16x16x32_bf16(kf1, qf[1], s, 0, 0, 0);
            sfr[sub] = s;
          }
          float sc[8];
#pragma unroll
          for (int sub = 0; sub < 2; ++sub)
#pragma unroll
            for (int r = 0; r < 4; ++r) {
              int key = kb + sub * 16 + 4 * g + r;
              float sv = sfr[sub][r] * 0.125f;
              sc[sub * 4 + r] = (key <= qrow) ? sv : -1e30f;
            }
          float pmax = sc[0];
#pragma unroll
          for (int e = 1; e < 8; ++e) pmax = fmaxf(pmax, sc[e]);
          pmax = fmaxf(pmax, __shfl_xor(pmax, 16));
          pmax = fmaxf(pmax, __shfl_xor(pmax, 32));
          if (__all(pmax <= m + 8.0f)) {
            float p[8], ps = 0.0f;
#pragma unroll
            for (int e = 0; e < 8; ++e) { p[e] = __expf(sc[e] - m); ps += p[e]; }
            ps += __shfl_xor(ps, 16);
            ps += __shfl_xor(ps, 32);
            lsum += ps;
            short8 pfr;
#pragma unroll
            for (int e = 0; e < 8; ++e) pfr[e] = (short)f2bf(p[e]);
#pragma unroll
            for (int nb = 0; nb < 4; ++nb) {
              const u16* vtp = &Vt[cur][(nb * 16 + fl) * 68 + i32 * 32 + 4 * g];
              short8 vf = mk8(*(const us4*)vtp, *(const us4*)(vtp + 16));
              oacc[nb] = __builtin_amdgcn_mfma_f32_16x16x32_bf16(pfr, vf, oacc[nb], 0, 0, 0);
            }
          } else {
            float mnew = fmaxf(m, pmax);
            float corr = __expf(m - mnew);
            float p[8], ps = 0.0f;
#pragma unroll
            for (int e = 0; e < 8; ++e) { p[e] = __expf(sc[e] - mnew); ps += p[e]; }
            ps += __shfl_xor(ps, 16);
            ps += __shfl_xor(ps, 32);
            lsum = lsum * corr + ps;
            m = mnew;
            float cr[4];
#pragma unroll
            for (int r = 0; r < 4; ++r) cr[r] = __shfl(corr, 4 * g + r);
#pragma unroll
            for (int nb = 0; nb < 4; ++nb)
#pragma unroll
              for (int r = 0; r < 4; ++r) oacc[nb][r] *= cr[r];
            short8 pfr;
#pragma unroll
            for (int e = 0; e < 8; ++e) pfr[e] = (short)f2bf(p[e]);
#pragma unroll
            for (int nb = 0; nb < 4; ++nb) {
              const u16* vtp = &Vt[cur][(nb * 16 + fl) * 68 + i32 * 32 + 4 * g];
              short8 vf = mk8(*(const us4*)vtp, *(const us4*)(vtp + 16));
              oacc[nb] = __builtin_amdgcn_mfma_f32_16x16x32_bf16(pfr, vf, oacc[nb], 0, 0, 0);
            }
          }
        }
      }
      if (pf) {
        __syncthreads();
#pragma unroll
        for (int qi = 0; qi < 4; ++qi)
#pragma unroll
          for (int i = 0; i < 4; ++i) Vt[cur ^ 1][(vd + qi * 4 + i) * 68 + vr] = vvn[qi][i];
        __syncthreads();
        cur ^= 1;
      }
    }
  }

  // store partials (unnormalized)
  const size_t part = ((size_t)bh * 16 + qb) * 2 + sp;
  float* ob = pO + part * 4096;
  float* ml = pML + part * 128;
#pragma unroll
  for (int nb = 0; nb < 4; ++nb)
#pragma unroll
    for (int r = 0; r < 4; ++r)
      ob[(w * 16 + 4 * g + r) * 64 + nb * 16 + fl] = oacc[nb][r];
  if (g == 0) {
    ml[w * 16 + fl] = m;
    ml[64 + w * 16 + fl] = lsum;
  }
}

// ---------------- split reduce ----------------
__global__ __launch_bounds__(256) void k_ared(const float* __restrict__ pO,
                                              const float* __restrict__ pML,
                                              u16* __restrict__ O) {
  __shared__ float w0s[64], w1s[64], iLs[64];
  const int qb = blockIdx.x, bh = blockIdx.y;
  const int b = bh / NH, hh = bh % NH;
  const int tid = threadIdx.x;
  const size_t p0 = ((size_t)bh * 16 + qb) * 2;
  if (tid < 64) {
    float m0 = pML[p0 * 128 + tid], l0 = pML[p0 * 128 + 64 + tid];
    float m1 = pML[(p0 + 1) * 128 + tid], l1 = pML[(p0 + 1) * 128 + 64 + tid];
    float M = fmaxf(m0, m1);
    float w0 = __expf(m0 - M), w1 = __expf(m1 - M);
    w0s[tid] = w0; w1s[tid] = w1;
    iLs[tid] = 1.0f / (l0 * w0 + l1 * w1);
  }
  __syncthreads();
  const float* O0 = pO + p0 * 4096;
  const float* O1 = pO + (p0 + 1) * 4096;
  for (int i = tid; i < 4096; i += 256) {
    int row = i >> 6, d = i & 63;
    float v = (O0[i] * w0s[row] + O1[i] * w1s[row]) * iLs[row];
    O[(size_t)(b * SEQ + qb * 64 + row) * DMODEL + hh * DHEAD + d] = f2bf(v);
  }
}

// ---------------- launcher ----------------
extern "C" void kernel_launch(void* const* d_in, const int* in_sizes, int n_in,
                              void* d_out, int out_size, void* d_ws, size_t ws_size,
                              hipStream_t stream) {
  const int*   x    = (const int*)d_in[0];
  const float* emb  = (const float*)d_in[1];
  const float* pos  = (const float*)d_in[2];
  const float* ln1g = (const float*)d_in[3];
  const float* ln1b = (const float*)d_in[4];
  const float* wq   = (const float*)d_in[5];
  const float* bq   = (const float*)d_in[6];
  const float* wk   = (const float*)d_in[7];
  const float* bk   = (const float*)d_in[8];
  const float* wv   = (const float*)d_in[9];
  const float* bv   = (const float*)d_in[10];
  const float* wo   = (const float*)d_in[11];
  const float* bo   = (const float*)d_in[12];
  const float* ln2g = (const float*)d_in[13];
  const float* ln2b = (const float*)d_in[14];
  const float* win  = (const float*)d_in[15];
  const float* bin  = (const float*)d_in[16];
  const float* wout = (const float*)d_in[17];
  const float* bout = (const float*)d_in[18];
  const float* lnfg = (const float*)d_in[19];
  const float* lnfb = (const float*)d_in[20];
  const float* outw = (const float*)d_in[21];

  char* w8 = (char*)d_ws;
  float* h    = (float*)(w8);                 // 6291456
  u16* abuf   = (u16*)(w8 + 6291456);         // 3145728
  u16* qkv    = (u16*)(w8 + 9437184);         // 9437184
  u16* obuf   = (u16*)(w8 + 18874368);        // 3145728
  u16* ffbuf  = (u16*)(w8 + 9437184);         // alias qkv+obuf
  u16* wqkvT  = (u16*)(w8 + 22020096);        // 3538944
  u16* woT    = (u16*)(w8 + 25559040);        // 1179648
  u16* winT   = (u16*)(w8 + 26738688);        // 4718592
  u16* woutT  = (u16*)(w8 + 31457280);        // 4718592
  u16* outwT  = (u16*)(w8 + 36175872);        // 786432
  float* bqkv = (float*)(w8 + 36962304);      // 36864
  float* pO   = (float*)(w8 + 36999168);      // 12582912
  float* pML  = (float*)(w8 + 49582080);      // 393216

  k_embed<<<TKN, 256, 0, stream>>>(x, emb, pos, h);
  k_packb<<<36, 256, 0, stream>>>(bq, bk, bv, bqkv);
  k_cvtT<<<dim3(12, 8), 256, 0, stream>>>(outw, outwT, DMODEL, NVOCAB);

  for (int l = 0; l < NL; ++l) {
    k_cvtL<<<1728, 256, 0, stream>>>(
        wq + (size_t)l * DMODEL * DMODEL, wk + (size_t)l * DMODEL * DMODEL,
        wv + (size_t)l * DMODEL * DMODEL, wo + (size_t)l * DMODEL * DMODEL,
        win + (size_t)l * DMODEL * DFF, wout + (size_t)l * DFF * DMODEL,
        wqkvT, woT, winT, woutT);

    k_ln<<<TKN, 256, 0, stream>>>(h, ln1g + l * DMODEL, ln1b + l * DMODEL, abuf);
    k_mm<0, 128><<<dim3(NQKV / 128, TKN / 128), 256, 0, stream>>>(
        abuf, wqkvT, bqkv + l * NQKV, qkv, NQKV, DMODEL);
    k_attn<<<dim3(SEQ / 64, 2 * NH, 2), 256, 0, stream>>>(qkv, pO, pML);
    k_ared<<<dim3(SEQ / 64, 2 * NH), 256, 0, stream>>>(pO, pML, obuf);
    k_mm<1, 64><<<dim3(DMODEL / 128, TKN / 64), 256, 0, stream>>>(
        obuf, woT, bo + l * DMODEL, h, DMODEL, DMODEL);
    k_ln<<<TKN, 256, 0, stream>>>(h, ln2g + l * DMODEL, ln2b + l * DMODEL, abuf);
    k_mm<2, 128><<<dim3(DFF / 128, TKN / 128), 256, 0, stream>>>(
        abuf, winT, bin + l * DFF, ffbuf, DFF, DMODEL);
    k_mm<1, 64><<<dim3(DMODEL / 128, TKN / 64), 256, 0, stream>>>(
        ffbuf, woutT, bout + l * DMODEL, h, DMODEL, DFF);
  }

  k_ln<<<TKN, 256, 0, stream>>>(h, lnfg, lnfb, abuf);
  k_mm<3, 64><<<dim3(NVOCAB / 128, TKN / 64), 256, 0, stream>>>(
      abuf, outwT, nullptr, d_out, NVOCAB, DMODEL);
}

// Round 7
// 709.802 us; speedup vs baseline: 2.8363x; 1.1591x over previous
//
#include <hip/hip_runtime.h>
#include <hip/hip_bf16.h>

// GPT forward: L=4, B=2, S=1024, D=768, H=12, DK=64, DI=3072, V=512
// R7: grid-shaping for TLP — BN=64 tiles, split-K (atomicAdd f32) for
//     O-proj (z=2) and MLP-out (z=4); logits BM=64.

#define TKN    2048
#define DMODEL 768
#define SEQ    1024
#define NH     12
#define DHEAD  64
#define DFF    3072
#define NL     4
#define NVOCAB 512
#define NQKV   2304

typedef unsigned short u16;
typedef __attribute__((ext_vector_type(4))) float f32x4;
typedef __attribute__((ext_vector_type(8))) short short8;
typedef __attribute__((ext_vector_type(4))) unsigned short us4;

__device__ __forceinline__ u16 f2bf(float f) {
  unsigned u = __builtin_bit_cast(unsigned, f);
  u += 0x7fffu + ((u >> 16) & 1u);   // RNE
  return (u16)(u >> 16);
}

__device__ __forceinline__ short8 mk8(us4 lo, us4 hi) {
  short8 r;
  r[0] = (short)lo[0]; r[1] = (short)lo[1]; r[2] = (short)lo[2]; r[3] = (short)lo[3];
  r[4] = (short)hi[0]; r[5] = (short)hi[1]; r[6] = (short)hi[2]; r[7] = (short)hi[3];
  return r;
}

__device__ __forceinline__ void gload16(const u16* g, u16* l) {
  __builtin_amdgcn_global_load_lds(
      (const __attribute__((address_space(1))) unsigned int*)g,
      (__attribute__((address_space(3))) unsigned int*)l, 16, 0, 0);
}

// ---------------- embedding ----------------
__global__ __launch_bounds__(256) void k_embed(const int* __restrict__ x,
                                               const float* __restrict__ emb,
                                               const float* __restrict__ pos,
                                               float* __restrict__ h) {
  int t = blockIdx.x;
  int s = t & (SEQ - 1);
  int id = x[t];
  int d = threadIdx.x;
#pragma unroll
  for (int j = 0; j < 3; ++j, d += 256)
    h[t * DMODEL + d] = emb[id * DMODEL + d] + pos[s * DMODEL + d];
}

// ---------------- layernorm (f32 in -> bf16 out) ----------------
__global__ __launch_bounds__(256) void k_ln(const float* __restrict__ h,
                                            const float* __restrict__ gam,
                                            const float* __restrict__ bet,
                                            u16* __restrict__ out) {
  __shared__ float sbuf[8];
  int row = blockIdx.x, tid = threadIdx.x;
  const float* hr = h + (size_t)row * DMODEL;
  float x0 = hr[tid], x1 = hr[tid + 256], x2 = hr[tid + 512];
  float s = x0 + x1 + x2;
#pragma unroll
  for (int off = 32; off > 0; off >>= 1) s += __shfl_down(s, off);
  if ((tid & 63) == 0) sbuf[tid >> 6] = s;
  __syncthreads();
  float mu = (sbuf[0] + sbuf[1] + sbuf[2] + sbuf[3]) * (1.0f / DMODEL);
  float d0 = x0 - mu, d1 = x1 - mu, d2 = x2 - mu;
  float v = d0 * d0 + d1 * d1 + d2 * d2;
#pragma unroll
  for (int off = 32; off > 0; off >>= 1) v += __shfl_down(v, off);
  if ((tid & 63) == 0) sbuf[4 + (tid >> 6)] = v;
  __syncthreads();
  float var = (sbuf[4] + sbuf[5] + sbuf[6] + sbuf[7]) * (1.0f / DMODEL);
  float rstd = rsqrtf(var + 1e-5f);
  size_t o = (size_t)row * DMODEL;
  out[o + tid]       = f2bf(d0 * rstd * gam[tid]       + bet[tid]);
  out[o + tid + 256] = f2bf(d1 * rstd * gam[tid + 256] + bet[tid + 256]);
  out[o + tid + 512] = f2bf(d2 * rstd * gam[tid + 512] + bet[tid + 512]);
}

// ---------------- 64x64 transpose-convert tile ----------------
__device__ __forceinline__ void cvt_tile(const float* __restrict__ src, int ldS,
                                         int k0, int n0src,
                                         u16* __restrict__ dst, int ldD, int n0dst,
                                         int tid, u16 (*tl)[72]) {
  int kr = tid >> 2, nj = (tid & 3) << 4;
  const float* sp = src + (size_t)(k0 + kr) * ldS + n0src + nj;
  float4 a0 = ((const float4*)sp)[0];
  float4 a1 = ((const float4*)sp)[1];
  float4 a2 = ((const float4*)sp)[2];
  float4 a3 = ((const float4*)sp)[3];
  u16* tr = &tl[kr][nj];
  tr[0]=f2bf(a0.x); tr[1]=f2bf(a0.y); tr[2]=f2bf(a0.z); tr[3]=f2bf(a0.w);
  tr[4]=f2bf(a1.x); tr[5]=f2bf(a1.y); tr[6]=f2bf(a1.z); tr[7]=f2bf(a1.w);
  tr[8]=f2bf(a2.x); tr[9]=f2bf(a2.y); tr[10]=f2bf(a2.z); tr[11]=f2bf(a2.w);
  tr[12]=f2bf(a3.x); tr[13]=f2bf(a3.y); tr[14]=f2bf(a3.z); tr[15]=f2bf(a3.w);
  __syncthreads();
  int nr = tid >> 2, kj = (tid & 3) << 4;
  us4 o[4];
#pragma unroll
  for (int c = 0; c < 4; ++c)
#pragma unroll
    for (int i = 0; i < 4; ++i) o[c][i] = tl[kj + c * 4 + i][nr];
  u16* dp = dst + (size_t)(n0dst + nr) * ldD + k0 + kj;
  ((us4*)dp)[0] = o[0]; ((us4*)dp)[1] = o[1];
  ((us4*)dp)[2] = o[2]; ((us4*)dp)[3] = o[3];
}

// fused per-layer weight conversion: 1728 tiles
__global__ __launch_bounds__(256) void k_cvtL(const float* __restrict__ wq,
                                              const float* __restrict__ wk,
                                              const float* __restrict__ wv,
                                              const float* __restrict__ wo,
                                              const float* __restrict__ win,
                                              const float* __restrict__ wout,
                                              u16* __restrict__ wqkvT,
                                              u16* __restrict__ woT,
                                              u16* __restrict__ winT,
                                              u16* __restrict__ woutT) {
  __shared__ u16 tl[64][72];
  int t = blockIdx.x, tid = threadIdx.x;
  if (t < 432) {
    int kt = t % 12, ntile = t / 12;
    int gn0 = ntile * 64, sel = gn0 / DMODEL;
    const float* src = sel == 0 ? wq : sel == 1 ? wk : wv;
    cvt_tile(src, DMODEL, kt * 64, gn0 - sel * DMODEL, wqkvT, DMODEL, gn0, tid, tl);
  } else if (t < 576) {
    int t2 = t - 432, kt = t2 % 12, nt = t2 / 12;
    cvt_tile(wo, DMODEL, kt * 64, nt * 64, woT, DMODEL, nt * 64, tid, tl);
  } else if (t < 1152) {
    int t3 = t - 576, kt = t3 % 12, nt = t3 / 12;
    cvt_tile(win, DFF, kt * 64, nt * 64, winT, DMODEL, nt * 64, tid, tl);
  } else {
    int t4 = t - 1152, kt = t4 % 48, nt = t4 / 48;
    cvt_tile(wout, DMODEL, kt * 64, nt * 64, woutT, DFF, nt * 64, tid, tl);
  }
}

__global__ __launch_bounds__(256) void k_cvtT(const float* __restrict__ src,
                                              u16* __restrict__ dst,
                                              int K, int N) {
  __shared__ u16 tl[64][72];
  cvt_tile(src, N, blockIdx.x * 64, blockIdx.y * 64, dst, K, blockIdx.y * 64,
           threadIdx.x, tl);
}

__global__ __launch_bounds__(256) void k_packb(const float* __restrict__ bq,
                                               const float* __restrict__ bk,
                                               const float* __restrict__ bv,
                                               float* __restrict__ dst) {
  int i = blockIdx.x * 256 + threadIdx.x;
  if (i < NL * NQKV) {
    int l = i / NQKV, j = i - l * NQKV;
    float v = j < DMODEL ? bq[l * DMODEL + j]
            : j < 2 * DMODEL ? bk[l * DMODEL + j - DMODEL]
            : bv[l * DMODEL + j - 2 * DMODEL];
    dst[i] = v;
  }
}

// ---------------- GEMM: C[M,N] = A[M,K](bf16) * BT[N,K](bf16) ----------------
// EP 0: bf16 = acc+bias     EP 1: atomicAdd f32 (+bias on split 0)
// EP 2: bf16 = gelu(acc+b)  EP 3: f32 = acc
// BM x BN tile, BK=64, 4 waves (2x2), wave tile (BM/2)x(BN/2).
// Split-K via gridDim.z (K % (64*z) == 0).
template <int EP, int BM, int BN>
__global__ __launch_bounds__(256) void k_mm(const u16* __restrict__ A,
                                            const u16* __restrict__ BT,
                                            const float* __restrict__ bias,
                                            void* __restrict__ outp,
                                            int N, int K) {
  constexpr int MI = BM / 32;   // A frag count per wave == A stage issues
  constexpr int NJ = BN / 32;   // B frag count per wave == B stage issues
  __shared__ __align__(16) u16 As[2][BM * 64];
  __shared__ __align__(16) u16 Bs[2][BN * 64];
  const int nbx = gridDim.x;
  int lin = blockIdx.y * nbx + blockIdx.x;
  const int chunk = (nbx * gridDim.y) >> 3;
  lin = (lin & 7) * chunk + (lin >> 3);
  const int bn = (lin % nbx) * BN, bm = (lin / nbx) * BM;

  const int tid = threadIdx.x, lane = tid & 63, wid = tid >> 6;
  const int g = lane >> 4, fl = lane & 15;
  const int wm = wid >> 1, wn = wid & 1;

  const int srow = wid * 8 + (lane >> 3);
  const int scol = ((lane & 7) ^ (lane >> 3)) << 3;
  const u16* ag = A + (size_t)(bm + srow) * K + scol;
  const u16* bg = BT + (size_t)(bn + srow) * K + scol;

  f32x4 acc[MI][NJ] = {};
  const int sw = (fl & 7) << 4;

  auto stage = [&](int buf, int kk) {
#pragma unroll
    for (int is = 0; is < MI; ++is)
      gload16(ag + kk + (size_t)is * 32 * K, &As[buf][wid * 512 + is * 2048]);
#pragma unroll
    for (int is = 0; is < NJ; ++is)
      gload16(bg + kk + (size_t)is * 32 * K, &Bs[buf][wid * 512 + is * 2048]);
  };

  const int ks = K / gridDim.z;          // per-split K extent
  const int kb0 = blockIdx.z * ks;
  const int nk = ks >> 6;
  stage(0, kb0);
  __syncthreads();
  int cur = 0;
  for (int kt = 0; kt < nk; ++kt) {
    if (kt + 1 < nk) stage(cur ^ 1, kb0 + ((kt + 1) << 6));
#pragma unroll
    for (int k0 = 0; k0 < 64; k0 += 32) {
      const int bo = (k0 + 4 * g) * 2;
      short8 af[MI], bf[NJ];
#pragma unroll
      for (int i = 0; i < MI; ++i) {
        const char* base = (const char*)&As[cur][(wm * (BM / 2) + i * 16 + fl) * 64];
        af[i] = mk8(*(const us4*)(base + (bo ^ sw)),
                    *(const us4*)(base + ((bo + 32) ^ sw)));
      }
#pragma unroll
      for (int j = 0; j < NJ; ++j) {
        const char* base = (const char*)&Bs[cur][(wn * (BN / 2) + j * 16 + fl) * 64];
        bf[j] = mk8(*(const us4*)(base + (bo ^ sw)),
                    *(const us4*)(base + ((bo + 32) ^ sw)));
      }
#pragma unroll
      for (int i = 0; i < MI; ++i)
#pragma unroll
        for (int j = 0; j < NJ; ++j)
          acc[i][j] = __builtin_amdgcn_mfma_f32_16x16x32_bf16(af[i], bf[j], acc[i][j], 0, 0, 0);
    }
    __syncthreads();
    cur ^= 1;
  }

  const int row0 = bm + wm * (BM / 2) + 4 * g;
  const int col0 = bn + wn * (BN / 2) + fl;
#pragma unroll
  for (int j = 0; j < NJ; ++j) {
    int col = col0 + j * 16;
    float bv = (EP == 3) ? 0.0f : bias[col];
    if (EP == 1 && blockIdx.z != 0) bv = 0.0f;
#pragma unroll
    for (int i = 0; i < MI; ++i) {
#pragma unroll
      for (int r = 0; r < 4; ++r) {
        int row = row0 + i * 16 + r;
        float val = acc[i][j][r] + bv;
        size_t idx = (size_t)row * N + col;
        if (EP == 0) {
          ((u16*)outp)[idx] = f2bf(val);
        } else if (EP == 1) {
          atomicAdd(&((float*)outp)[idx], val);
        } else if (EP == 2) {
          float t = 0.7978845608028654f * (val + 0.044715f * val * val * val);
          ((u16*)outp)[idx] = f2bf(0.5f * val * (1.0f + tanhf(t)));
        } else {
          ((float*)outp)[idx] = val;
        }
      }
    }
  }
}

// ---------------- flash attention, key-split partials ----------------
__global__ __launch_bounds__(256) void k_attn(const u16* __restrict__ qkv,
                                              float* __restrict__ pO,
                                              float* __restrict__ pML) {
  __shared__ u16 Vt[2][DHEAD * 68];
  int lin = blockIdx.y * gridDim.x + blockIdx.x;
  const int chunk = (gridDim.x * gridDim.y) >> 3;
  lin = (lin & 7) * chunk + (lin >> 3);
  const int qb = lin % gridDim.x;
  const int bh = lin / gridDim.x;
  const int sp = blockIdx.z;
  const int b = bh / NH, hh = bh % NH;
  const int tid = threadIdx.x, lane = tid & 63, w = tid >> 6;
  const int g = lane >> 4, fl = lane & 15;
  const int qrow = qb * 64 + w * 16 + fl;
  const u16* qp = qkv + (size_t)(b * SEQ + qrow) * NQKV + hh * DHEAD;

  short8 qf[2];
#pragma unroll
  for (int hf = 0; hf < 2; ++hf) {
    us4 lo = *(const us4*)(qp + hf * 32 + 4 * g);
    us4 hi = *(const us4*)(qp + hf * 32 + 16 + 4 * g);
    qf[hf] = mk8(lo, hi);
  }

  float m = -1e30f, lsum = 0.0f;
  f32x4 oacc[4] = {};
  const int qmaxw = qb * 64 + w * 16 + 15;
  const int vr = tid >> 2, vd = (tid & 3) << 4;
  const u16* vbase = qkv + (size_t)(b * SEQ + vr) * NQKV + 2 * DMODEL + hh * DHEAD + vd;
  const u16* kbase0 = qkv + (size_t)(b * SEQ) * NQKV + DMODEL + hh * DHEAD;

  const int nt = qb + 1;
  const int t_lo = (sp * nt) >> 1, t_hi = ((sp + 1) * nt) >> 1;

  if (t_lo < t_hi) {
    {
      const u16* vp = vbase + (size_t)t_lo * 64 * NQKV;
      us4 vv[4];
#pragma unroll
      for (int qi = 0; qi < 4; ++qi) vv[qi] = *(const us4*)(vp + qi * 4);
#pragma unroll
      for (int qi = 0; qi < 4; ++qi)
#pragma unroll
        for (int i = 0; i < 4; ++i) Vt[0][(vd + qi * 4 + i) * 68 + vr] = vv[qi][i];
    }
    __syncthreads();
    int cur = 0;
    for (int t64 = t_lo; t64 < t_hi; ++t64) {
      const u16* kb64 = kbase0 + (size_t)t64 * 64 * NQKV;
      us4 kv[4][4];
#pragma unroll
      for (int q4 = 0; q4 < 4; ++q4) {
        const u16* kp = kb64 + (size_t)(q4 * 16 + fl) * NQKV;
#pragma unroll
        for (int j = 0; j < 4; ++j) kv[q4][j] = *(const us4*)(kp + j * 16 + 4 * g);
      }
      const bool pf = (t64 + 1 < t_hi);
      us4 vvn[4];
      if (pf) {
        const u16* vp = vbase + (size_t)(t64 + 1) * 64 * NQKV;
#pragma unroll
        for (int qi = 0; qi < 4; ++qi) vvn[qi] = *(const us4*)(vp + qi * 4);
      }

#pragma unroll
      for (int i32 = 0; i32 < 2; ++i32) {
        int kb = t64 * 64 + i32 * 32;
        if (kb <= qmaxw) {
          f32x4 sfr[2];
#pragma unroll
          for (int sub = 0; sub < 2; ++sub) {
            int q4 = i32 * 2 + sub;
            short8 kf0 = mk8(kv[q4][0], kv[q4][1]);
            short8 kf1 = mk8(kv[q4][2], kv[q4][3]);
            f32x4 s = {};
            s = __builtin_amdgcn_mfma_f32_16x16x32_bf16(kf0, qf[0], s, 0, 0, 0);
            s = __builtin_amdgcn_mfma_f32_16x16x32_bf16(kf1, qf[1], s, 0, 0, 0);
            sfr[sub] = s;
          }
          float sc[8];
#pragma unroll
          for (int sub = 0; sub < 2; ++sub)
#pragma unroll
            for (int r = 0; r < 4; ++r) {
              int key = kb + sub * 16 + 4 * g + r;
              float sv = sfr[sub][r] * 0.125f;
              sc[sub * 4 + r] = (key <= qrow) ? sv : -1e30f;
            }
          float pmax = sc[0];
#pragma unroll
          for (int e = 1; e < 8; ++e) pmax = fmaxf(pmax, sc[e]);
          pmax = fmaxf(pmax, __shfl_xor(pmax, 16));
          pmax = fmaxf(pmax, __shfl_xor(pmax, 32));
          if (__all(pmax <= m + 8.0f)) {
            float p[8], ps = 0.0f;
#pragma unroll
            for (int e = 0; e < 8; ++e) { p[e] = __expf(sc[e] - m); ps += p[e]; }
            ps += __shfl_xor(ps, 16);
            ps += __shfl_xor(ps, 32);
            lsum += ps;
            short8 pfr;
#pragma unroll
            for (int e = 0; e < 8; ++e) pfr[e] = (short)f2bf(p[e]);
#pragma unroll
            for (int nb = 0; nb < 4; ++nb) {
              const u16* vtp = &Vt[cur][(nb * 16 + fl) * 68 + i32 * 32 + 4 * g];
              short8 vf = mk8(*(const us4*)vtp, *(const us4*)(vtp + 16));
              oacc[nb] = __builtin_amdgcn_mfma_f32_16x16x32_bf16(pfr, vf, oacc[nb], 0, 0, 0);
            }
          } else {
            float mnew = fmaxf(m, pmax);
            float corr = __expf(m - mnew);
            float p[8], ps = 0.0f;
#pragma unroll
            for (int e = 0; e < 8; ++e) { p[e] = __expf(sc[e] - mnew); ps += p[e]; }
            ps += __shfl_xor(ps, 16);
            ps += __shfl_xor(ps, 32);
            lsum = lsum * corr + ps;
            m = mnew;
            float cr[4];
#pragma unroll
            for (int r = 0; r < 4; ++r) cr[r] = __shfl(corr, 4 * g + r);
#pragma unroll
            for (int nb = 0; nb < 4; ++nb)
#pragma unroll
              for (int r = 0; r < 4; ++r) oacc[nb][r] *= cr[r];
            short8 pfr;
#pragma unroll
            for (int e = 0; e < 8; ++e) pfr[e] = (short)f2bf(p[e]);
#pragma unroll
            for (int nb = 0; nb < 4; ++nb) {
              const u16* vtp = &Vt[cur][(nb * 16 + fl) * 68 + i32 * 32 + 4 * g];
              short8 vf = mk8(*(const us4*)vtp, *(const us4*)(vtp + 16));
              oacc[nb] = __builtin_amdgcn_mfma_f32_16x16x32_bf16(pfr, vf, oacc[nb], 0, 0, 0);
            }
          }
        }
      }
      if (pf) {
        __syncthreads();
#pragma unroll
        for (int qi = 0; qi < 4; ++qi)
#pragma unroll
          for (int i = 0; i < 4; ++i) Vt[cur ^ 1][(vd + qi * 4 + i) * 68 + vr] = vvn[qi][i];
        __syncthreads();
        cur ^= 1;
      }
    }
  }

  const size_t part = ((size_t)bh * 16 + qb) * 2 + sp;
  float* ob = pO + part * 4096;
  float* ml = pML + part * 128;
#pragma unroll
  for (int nb = 0; nb < 4; ++nb)
#pragma unroll
    for (int r = 0; r < 4; ++r)
      ob[(w * 16 + 4 * g + r) * 64 + nb * 16 + fl] = oacc[nb][r];
  if (g == 0) {
    ml[w * 16 + fl] = m;
    ml[64 + w * 16 + fl] = lsum;
  }
}

// ---------------- split reduce ----------------
__global__ __launch_bounds__(256) void k_ared(const float* __restrict__ pO,
                                              const float* __restrict__ pML,
                                              u16* __restrict__ O) {
  __shared__ float w0s[64], w1s[64], iLs[64];
  const int qb = blockIdx.x, bh = blockIdx.y;
  const int b = bh / NH, hh = bh % NH;
  const int tid = threadIdx.x;
  const size_t p0 = ((size_t)bh * 16 + qb) * 2;
  if (tid < 64) {
    float m0 = pML[p0 * 128 + tid], l0 = pML[p0 * 128 + 64 + tid];
    float m1 = pML[(p0 + 1) * 128 + tid], l1 = pML[(p0 + 1) * 128 + 64 + tid];
    float M = fmaxf(m0, m1);
    float w0 = __expf(m0 - M), w1 = __expf(m1 - M);
    w0s[tid] = w0; w1s[tid] = w1;
    iLs[tid] = 1.0f / (l0 * w0 + l1 * w1);
  }
  __syncthreads();
  const float* O0 = pO + p0 * 4096;
  const float* O1 = pO + (p0 + 1) * 4096;
  for (int i = tid; i < 4096; i += 256) {
    int row = i >> 6, d = i & 63;
    float v = (O0[i] * w0s[row] + O1[i] * w1s[row]) * iLs[row];
    O[(size_t)(b * SEQ + qb * 64 + row) * DMODEL + hh * DHEAD + d] = f2bf(v);
  }
}

// ---------------- launcher ----------------
extern "C" void kernel_launch(void* const* d_in, const int* in_sizes, int n_in,
                              void* d_out, int out_size, void* d_ws, size_t ws_size,
                              hipStream_t stream) {
  const int*   x    = (const int*)d_in[0];
  const float* emb  = (const float*)d_in[1];
  const float* pos  = (const float*)d_in[2];
  const float* ln1g = (const float*)d_in[3];
  const float* ln1b = (const float*)d_in[4];
  const float* wq   = (const float*)d_in[5];
  const float* bq   = (const float*)d_in[6];
  const float* wk   = (const float*)d_in[7];
  const float* bk   = (const float*)d_in[8];
  const float* wv   = (const float*)d_in[9];
  const float* bv   = (const float*)d_in[10];
  const float* wo   = (const float*)d_in[11];
  const float* bo   = (const float*)d_in[12];
  const float* ln2g = (const float*)d_in[13];
  const float* ln2b = (const float*)d_in[14];
  const float* win  = (const float*)d_in[15];
  const float* bin  = (const float*)d_in[16];
  const float* wout = (const float*)d_in[17];
  const float* bout = (const float*)d_in[18];
  const float* lnfg = (const float*)d_in[19];
  const float* lnfb = (const float*)d_in[20];
  const float* outw = (const float*)d_in[21];

  char* w8 = (char*)d_ws;
  float* h    = (float*)(w8);                 // 6291456
  u16* abuf   = (u16*)(w8 + 6291456);         // 3145728
  u16* qkv    = (u16*)(w8 + 9437184);         // 9437184
  u16* obuf   = (u16*)(w8 + 18874368);        // 3145728
  u16* ffbuf  = (u16*)(w8 + 9437184);         // alias qkv+obuf
  u16* wqkvT  = (u16*)(w8 + 22020096);        // 3538944
  u16* woT    = (u16*)(w8 + 25559040);        // 1179648
  u16* winT   = (u16*)(w8 + 26738688);        // 4718592
  u16* woutT  = (u16*)(w8 + 31457280);        // 4718592
  u16* outwT  = (u16*)(w8 + 36175872);        // 786432
  float* bqkv = (float*)(w8 + 36962304);      // 36864
  float* pO   = (float*)(w8 + 36999168);      // 12582912
  float* pML  = (float*)(w8 + 49582080);      // 393216

  k_embed<<<TKN, 256, 0, stream>>>(x, emb, pos, h);
  k_packb<<<36, 256, 0, stream>>>(bq, bk, bv, bqkv);
  k_cvtT<<<dim3(12, 8), 256, 0, stream>>>(outw, outwT, DMODEL, NVOCAB);

  for (int l = 0; l < NL; ++l) {
    k_cvtL<<<1728, 256, 0, stream>>>(
        wq + (size_t)l * DMODEL * DMODEL, wk + (size_t)l * DMODEL * DMODEL,
        wv + (size_t)l * DMODEL * DMODEL, wo + (size_t)l * DMODEL * DMODEL,
        win + (size_t)l * DMODEL * DFF, wout + (size_t)l * DFF * DMODEL,
        wqkvT, woT, winT, woutT);

    k_ln<<<TKN, 256, 0, stream>>>(h, ln1g + l * DMODEL, ln1b + l * DMODEL, abuf);
    k_mm<0, 128, 64><<<dim3(NQKV / 64, TKN / 128, 1), 256, 0, stream>>>(
        abuf, wqkvT, bqkv + l * NQKV, qkv, NQKV, DMODEL);
    k_attn<<<dim3(SEQ / 64, 2 * NH, 2), 256, 0, stream>>>(qkv, pO, pML);
    k_ared<<<dim3(SEQ / 64, 2 * NH), 256, 0, stream>>>(pO, pML, obuf);
    k_mm<1, 128, 64><<<dim3(DMODEL / 64, TKN / 128, 2), 256, 0, stream>>>(
        obuf, woT, bo + l * DMODEL, h, DMODEL, DMODEL);
    k_ln<<<TKN, 256, 0, stream>>>(h, ln2g + l * DMODEL, ln2b + l * DMODEL, abuf);
    k_mm<2, 128, 64><<<dim3(DFF / 64, TKN / 128, 1), 256, 0, stream>>>(
        abuf, winT, bin + l * DFF, ffbuf, DFF, DMODEL);
    k_mm<1, 128, 64><<<dim3(DMODEL / 64, TKN / 128, 4), 256, 0, stream>>>(
        ffbuf, woutT, bout + l * DMODEL, h, DMODEL, DFF);
  }

  k_ln<<<TKN, 256, 0, stream>>>(h, lnfg, lnfb, abuf);
  k_mm<3, 64, 64><<<dim3(NVOCAB / 64, TKN / 64, 1), 256, 0, stream>>>(
      abuf, outwT, nullptr, d_out, NVOCAB, DMODEL);
}